// Round 4
// baseline (250.256 us; speedup 1.0000x reference)
//
#include <hip/hip_runtime.h>
#include <hip/hip_bf16.h>
#include <cmath>

typedef __bf16 bf16_t;
typedef __attribute__((ext_vector_type(8))) __bf16 bf16x8;
typedef __attribute__((ext_vector_type(4))) float f32x4;
typedef __attribute__((ext_vector_type(4))) short s16x4;

#define S_LEN 2048
#define DMODEL 2048
#define KVDIM 512
#define NHEADS 32
#define NKV 8
#define HDIM 64

__device__ inline f32x4 zero4() { f32x4 z; z[0]=0.f; z[1]=0.f; z[2]=0.f; z[3]=0.f; return z; }

// Inputs are fp32 (established R2-R6: bf16 misread would NaN; we pass at 1.46e-3).
// One dispatch converts all 5 tensors to bf16. 2048 elems/block:
// x 2048 | Wq 2048 | Wk 512 | Wv 512 | Wo 2048 blocks (7168 total).
__global__ void convert_all(const float* __restrict__ s0, bf16_t* __restrict__ d0,
                            const float* __restrict__ s1, bf16_t* __restrict__ d1,
                            const float* __restrict__ s2, bf16_t* __restrict__ d2,
                            const float* __restrict__ s3, bf16_t* __restrict__ d3,
                            const float* __restrict__ s4, bf16_t* __restrict__ d4) {
  int b = blockIdx.x;
  const float* src; bf16_t* dst; int boff;
  if      (b < 2048) { src = s0; dst = d0; boff = b; }
  else if (b < 4096) { src = s1; dst = d1; boff = b - 2048; }
  else if (b < 4608) { src = s2; dst = d2; boff = b - 4096; }
  else if (b < 5120) { src = s3; dst = d3; boff = b - 4608; }
  else               { src = s4; dst = d4; boff = b - 5120; }
  int idx = (boff * 256 + threadIdx.x) * 8;
  bf16x8 v;
#pragma unroll
  for (int j = 0; j < 8; j++) v[j] = (bf16_t)src[idx + j];
  *(bf16x8*)(dst + idx) = v;
}

// GEMM core: C = A(MxK) * Bt(NxK)^T, bf16 in, fp32 accum. Tile 128 x BN, BK=64,
// 4 waves 2x2 (wave covers 64 x BN/2). BN=64 doubles block count vs BN=128 ->
// 2-3 blocks/CU residency at these matrix sizes (m102: 128^2 @N=2048 is 1/CU-starved).
template <int BN, bool F32OUT>
__device__ __forceinline__ void gemm_core(const bf16_t* __restrict__ A,
                                          const bf16_t* __restrict__ Bt,
                                          void* __restrict__ Cout,
                                          int N, int K, int bm, int bn) {
  constexpr int NT_W = BN / 32;    // 16-col acc tiles per wave
  __shared__ __attribute__((aligned(16))) bf16_t As[128 * 64];
  __shared__ __attribute__((aligned(16))) bf16_t Bs[BN * 64];
  const int tid  = threadIdx.x;
  const int wave = tid >> 6, lane = tid & 63;
  const int wm = wave >> 1, wn = wave & 1;
  const int quad = lane >> 4, lr = lane & 15;
  const int srow = lane >> 3, scol = lane & 7;

  f32x4 acc[4][NT_W];
#pragma unroll
  for (int i = 0; i < 4; i++)
#pragma unroll
    for (int j = 0; j < NT_W; j++) acc[i][j] = zero4();

  for (int k0 = 0; k0 < K; k0 += 64) {
#pragma unroll
    for (int i = 0; i < 4; i++) {
      const bf16_t* gA = A + (size_t)(bm + i * 32 + wave * 8 + srow) * K + k0 + scol * 8;
      bf16_t* lA = As + (i * 32 + wave * 8) * 64;
      __builtin_amdgcn_global_load_lds((const __attribute__((address_space(1))) void*)gA,
                                       (__attribute__((address_space(3))) void*)lA, 16, 0, 0);
    }
#pragma unroll
    for (int i = 0; i < BN / 32; i++) {
      const bf16_t* gB = Bt + (size_t)(bn + i * 32 + wave * 8 + srow) * K + k0 + scol * 8;
      bf16_t* lB = Bs + (i * 32 + wave * 8) * 64;
      __builtin_amdgcn_global_load_lds((const __attribute__((address_space(1))) void*)gB,
                                       (__attribute__((address_space(3))) void*)lB, 16, 0, 0);
    }
    __syncthreads();
#pragma unroll
    for (int ks = 0; ks < 2; ks++) {
      bf16x8 a[4], b[NT_W];
#pragma unroll
      for (int mt = 0; mt < 4; mt++)
        a[mt] = *(const bf16x8*)&As[(wm * 64 + mt * 16 + lr) * 64 + ks * 32 + quad * 8];
#pragma unroll
      for (int nt = 0; nt < NT_W; nt++)
        b[nt] = *(const bf16x8*)&Bs[(wn * (BN / 2) + nt * 16 + lr) * 64 + ks * 32 + quad * 8];
#pragma unroll
      for (int mt = 0; mt < 4; mt++)
#pragma unroll
        for (int nt = 0; nt < NT_W; nt++)
          acc[mt][nt] = __builtin_amdgcn_mfma_f32_16x16x32_bf16(a[mt], b[nt], acc[mt][nt], 0, 0, 0);
    }
    __syncthreads();
  }

#pragma unroll
  for (int mt = 0; mt < 4; mt++)
#pragma unroll
    for (int nt = 0; nt < NT_W; nt++)
#pragma unroll
      for (int r = 0; r < 4; r++) {
        int row = bm + wm * 64 + mt * 16 + quad * 4 + r;
        int col = bn + wn * (BN / 2) + nt * 16 + lr;
        if (F32OUT) ((float*)Cout)[(size_t)row * N + col] = acc[mt][nt][r];
        else ((bf16_t*)Cout)[(size_t)row * N + col] = (bf16_t)acc[mt][nt][r];
      }
}

// All three projections, one dispatch, 768 blocks of 128x64 tiles:
// 0..511: q = x Wq^T; 512..639: k = x Wk^T; 640..767: vT = Wv x^T.
__global__ __launch_bounds__(256) void gemm_proj(const bf16_t* __restrict__ xb,
                                                 const bf16_t* __restrict__ Wqb,
                                                 const bf16_t* __restrict__ Wkb,
                                                 const bf16_t* __restrict__ Wvb,
                                                 bf16_t* __restrict__ qb,
                                                 bf16_t* __restrict__ kb,
                                                 bf16_t* __restrict__ vb) {
  int b = blockIdx.x;
  if (b < 512) {
    gemm_core<64, false>(xb, Wqb, qb, 2048, 2048, (b >> 5) * 128, (b & 31) * 64);
  } else if (b < 640) {
    int r = b - 512;
    gemm_core<64, false>(xb, Wkb, kb, 512, 2048, (r >> 3) * 128, (r & 7) * 64);
  } else {
    int r = b - 640;
    gemm_core<64, false>(Wvb, xb, vb, 2048, 2048, (r >> 5) * 128, (r & 31) * 64);
  }
}

// Final projection: out = attn_out Wo^T, fp32 stores. 512 blocks of 128x64.
__global__ __launch_bounds__(256) void gemm_out(const bf16_t* __restrict__ A,
                                                const bf16_t* __restrict__ Bt,
                                                float* __restrict__ C) {
  int b = blockIdx.x;
  gemm_core<64, true>(A, Bt, C, 2048, 2048, (b >> 5) * 128, (b & 31) * 64);
}

// RoPE on k only (q is roped in-register inside attn).
__global__ void rope_k(bf16_t* __restrict__ kb) {
  int idx = blockIdx.x * 256 + threadIdx.x;
  int s = idx >> 8;                 // 256 pairs per row (KVDIM/2)
  int rem = idx & 255;
  int head = rem >> 5;
  int i = rem & 31;
  float freq = __expf(-0.2878231366f * (float)i);   // 10000^(-i/32)
  float ang = (float)s * freq;
  float sn, cs;
  sincosf(ang, &sn, &cs);
  size_t base = (size_t)s * KVDIM + head * 64 + i;
  float x0 = (float)kb[base];
  float x1 = (float)kb[base + 32];
  kb[base]      = (bf16_t)(x0 * cs - x1 * sn);
  kb[base + 32] = (bf16_t)(x1 * cs + x0 * sn);
}

// Flash attention, S^T formulation, KB=128 key tiles, 32 q-rows/wave (R7).
// R10: key-split ACROSS BLOCKS (R8/R9's in-block 512-thread/64KB-LDS split
// never packed 2 blocks/CU: occupancy stayed ~21%, dur regressed 67->79us).
// Back to R7's proven 256-thread/32.8KB/96-VGPR shape; grid (16 qt, 32 h,
// 2 key-halves) = 1024 blocks = 4 blocks/CU (LDS 4x32.8=131KB<160, VGPR
// 4x96<512) => 4 waves/SIMD, 2x R7 concurrency, inner loop untouched.
// Each block emits unnormalized fp32 O-partial + l-partial (exactly additive,
// no running max); combine_kernel sums halves + normalizes -> bf16 ab.
__global__ __launch_bounds__(256) void attn_kernel(const bf16_t* __restrict__ q,
                                                   const bf16_t* __restrict__ k,
                                                   const bf16_t* __restrict__ vT,
                                                   float* __restrict__ Op0,
                                                   float* __restrict__ Op1,
                                                   float* __restrict__ l01) {
  __shared__ __attribute__((aligned(16))) bf16_t Ks[128 * 64];   // [key][d]
  __shared__ __attribute__((aligned(16))) bf16_t Vs[64 * 128];   // [d][key]
  const int tid  = threadIdx.x;
  const int wave = tid >> 6, lane = tid & 63;
  const int quad = lane >> 4, lr = lane & 15;
  const int srow = lane >> 3, scol = lane & 7;   // K staging: 8 rows x 8 chunks
  const int vrow = lane >> 4, vcol = lane & 15;  // V staging: 4 rows x 16 chunks
  const int cg = scol ^ srow;                    // K swizzle (row&7 == srow)
  const int qt = blockIdx.x, h = blockIdx.y, kw = blockIdx.z;
  const int hkv = h >> 2;
  const int qrow0 = qt * 128 + wave * 32;        // 32 q-rows per wave
  const int sw = lr & 7;
  const int c0 = (quad ^ sw) * 8;                // K-frag chunk for d<32
  const int c1 = ((quad + 4) ^ sw) * 8;          // d>=32
  float* Op = kw ? Op1 : Op0;
  float* lp = l01 + kw * (S_LEN * NHEADS);

  // Q B-fragments + in-register RoPE for both 16-row sets
  // (lane holds the exact (d, d+32) pair).
  bf16x8 aqA0, aqA1, aqB0, aqB1;
#pragma unroll
  for (int set = 0; set < 2; set++) {
    int row = qrow0 + set * 16 + lr;
    const bf16_t* qp = q + (size_t)row * DMODEL + h * HDIM + quad * 8;
    bf16x8 r0 = *(const bf16x8*)qp;
    bf16x8 r1 = *(const bf16x8*)(qp + 32);
    float srow_f = (float)row;
    bf16x8 a0, a1;
#pragma unroll
    for (int j = 0; j < 8; j++) {
      float freq = __expf(-0.2878231366f * (float)(quad * 8 + j));
      float sn, cs;
      sincosf(srow_f * freq, &sn, &cs);
      float x0 = (float)r0[j], x1 = (float)r1[j];
      a0[j] = (bf16_t)(x0 * cs - x1 * sn);
      a1[j] = (bf16_t)(x1 * cs + x0 * sn);
    }
    if (set == 0) { aqA0 = a0; aqA1 = a1; } else { aqB0 = a0; aqB1 = a1; }
  }

  f32x4 OA[4], OB[4];         // O^T: (d = mt*16+quad*4+r, qrow = lr)
  float lA = 0.f, lB = 0.f;
#pragma unroll
  for (int mt = 0; mt < 4; mt++) { OA[mt] = zero4(); OB[mt] = zero4(); }

  const int kt0 = kw * (S_LEN / 2);
  for (int kt = kt0; kt < kt0 + S_LEN / 2; kt += 128) {
    // Stage K tile: 128 key-rows x 64 d. Wave w: rows w*32 + j*8 + srow.
#pragma unroll
    for (int j = 0; j < 4; j++) {
      const bf16_t* gK = k + (size_t)(kt + wave * 32 + j * 8 + srow) * KVDIM + hkv * HDIM + cg * 8;
      bf16_t* lK = Ks + (wave * 32 + j * 8) * 64;
      __builtin_amdgcn_global_load_lds((const __attribute__((address_space(1))) void*)gK,
                                       (__attribute__((address_space(3))) void*)lK, 16, 0, 0);
    }
    // Stage V^T tile: 64 d-rows x 128 keys. Wave w: rows w*16 + j*4 + vrow.
    // LDS[d][s] holds global chunk s ^ (d&7) (read side un-swizzles with lr&7).
#pragma unroll
    for (int j = 0; j < 4; j++) {
      int dg = wave * 16 + j * 4 + vrow;
      int cgv = vcol ^ (dg & 7);
      const bf16_t* gV = vT + (size_t)(hkv * HDIM + dg) * S_LEN + kt + cgv * 8;
      bf16_t* lV = Vs + (wave * 16 + j * 4) * 128;
      __builtin_amdgcn_global_load_lds((const __attribute__((address_space(1))) void*)gV,
                                       (__attribute__((address_space(3))) void*)lV, 16, 0, 0);
    }
    __syncthreads();   // vmcnt drain -> tiles ready

    // S^T = K Q^T over 8 key-subtiles; K frags shared by both q-sets.
    // exp fused per-nt so score regs stay transient (VGPR control).
    // exp2 with folded scale: exp(s*0.125) = exp2(s * 0.125*log2e).
    s16x4 bpA[8], bpB[8];
#pragma unroll
    for (int nt = 0; nt < 8; nt++) {
      const int rk = (nt * 16 + lr) * 64;
      bf16x8 kb0 = *(const bf16x8*)&Ks[rk + c0];
      bf16x8 kb1 = *(const bf16x8*)&Ks[rk + c1];
      f32x4 sA = zero4(), sB = zero4();
      sA = __builtin_amdgcn_mfma_f32_16x16x32_bf16(kb0, aqA0, sA, 0, 0, 0);
      sA = __builtin_amdgcn_mfma_f32_16x16x32_bf16(kb1, aqA1, sA, 0, 0, 0);
      sB = __builtin_amdgcn_mfma_f32_16x16x32_bf16(kb0, aqB0, sB, 0, 0, 0);
      sB = __builtin_amdgcn_mfma_f32_16x16x32_bf16(kb1, aqB1, sB, 0, 0, 0);
#pragma unroll
      for (int r = 0; r < 4; r++) {
        float pA = __builtin_amdgcn_exp2f(sA[r] * 0.1803368801f);
        lA += pA;
        bpA[nt][r] = __builtin_bit_cast(short, (bf16_t)pA);
        float pB = __builtin_amdgcn_exp2f(sB[r] * 0.1803368801f);
        lB += pB;
        bpB[nt][r] = __builtin_bit_cast(short, (bf16_t)pB);
      }
    }
    // O^T += V^T P^T: per nt load 4 V A-frags (b64, swizzle-slotted), feed BOTH sets
#pragma unroll
    for (int nt = 0; nt < 8; nt++) {
      const int slot = ((nt * 2 + (quad >> 1)) ^ sw) * 8 + (quad & 1) * 4;
      s16x4 av[4];
#pragma unroll
      for (int mt = 0; mt < 4; mt++)
        av[mt] = *(const s16x4*)&Vs[(mt * 16 + lr) * 128 + slot];
#pragma unroll
      for (int mt = 0; mt < 4; mt++) {
        OA[mt] = __builtin_amdgcn_mfma_f32_16x16x16bf16_1k(av[mt], bpA[nt], OA[mt], 0, 0, 0);
        OB[mt] = __builtin_amdgcn_mfma_f32_16x16x16bf16_1k(av[mt], bpB[nt], OB[mt], 0, 0, 0);
      }
    }
    __syncthreads();   // all waves done with Ks/Vs before next staging
  }

  // l for qrow lr: sum the 4 quad-partials
  lA += __shfl_xor(lA, 16);
  lA += __shfl_xor(lA, 32);
  lB += __shfl_xor(lB, 16);
  lB += __shfl_xor(lB, 32);

  // Emit unnormalized fp32 partials. Per mt, lanes {lr, lr+16, lr+32, lr+48}
  // cover 16 contiguous d for row lr -> 16 rows x 64B segments per store.
#pragma unroll
  for (int mt = 0; mt < 4; mt++) {
    *(f32x4*)&Op[(size_t)(qrow0 + lr) * DMODEL + h * HDIM + mt * 16 + quad * 4] = OA[mt];
    *(f32x4*)&Op[(size_t)(qrow0 + 16 + lr) * DMODEL + h * HDIM + mt * 16 + quad * 4] = OB[mt];
  }
  if (quad == 0) {
    lp[(qrow0 + lr) * NHEADS + h] = lA;
    lp[(qrow0 + 16 + lr) * NHEADS + h] = lB;
  }
}

// Sum the two key-half partials, normalize, emit bf16 attn output.
// 2048 blocks x 256 threads x 8 floats. 40MB traffic ~ 8us.
__global__ void combine_kernel(const float* __restrict__ O0,
                               const float* __restrict__ O1,
                               const float* __restrict__ l01,
                               bf16_t* __restrict__ ab) {
  int idx = (blockIdx.x * 256 + threadIdx.x) * 8;
  int row = idx >> 11;          // / DMODEL
  int h = (idx & 2047) >> 6;    // col / HDIM (8 | 64, so uniform per chunk)
  float inv = 1.f / (l01[row * NHEADS + h] + l01[S_LEN * NHEADS + row * NHEADS + h]);
  f32x4 a0 = *(const f32x4*)&O0[idx];
  f32x4 a1 = *(const f32x4*)&O0[idx + 4];
  f32x4 b0 = *(const f32x4*)&O1[idx];
  f32x4 b1 = *(const f32x4*)&O1[idx + 4];
  bf16x8 o;
#pragma unroll
  for (int r = 0; r < 4; r++) {
    o[r]     = (bf16_t)((a0[r] + b0[r]) * inv);
    o[4 + r] = (bf16_t)((a1[r] + b1[r]) * inv);
  }
  *(bf16x8*)&ab[idx] = o;
}

extern "C" void kernel_launch(void* const* d_in, const int* in_sizes, int n_in,
                              void* d_out, int out_size, void* d_ws, size_t ws_size,
                              hipStream_t stream) {
  (void)in_sizes; (void)n_in; (void)out_size; (void)ws_size;
  const float* x  = (const float*)d_in[0];
  const float* Wq = (const float*)d_in[1];
  const float* Wk = (const float*)d_in[2];
  const float* Wv = (const float*)d_in[3];
  const float* Wo = (const float*)d_in[4];

  bf16_t* xb  = (bf16_t*)d_ws;                       // 4M elems (8MB)
  bf16_t* Wqb = xb  + (size_t)4 * 1024 * 1024;       // 4M (8MB)
  bf16_t* Wkb = Wqb + (size_t)4 * 1024 * 1024;       // 1M (2MB)
  bf16_t* Wvb = Wkb + (size_t)1024 * 1024;           // 1M (2MB)
  bf16_t* qb  = Wvb + (size_t)1024 * 1024;           // 4M (8MB)
  bf16_t* kb  = qb  + (size_t)4 * 1024 * 1024;       // 1M (2MB)
  bf16_t* vb  = kb  + (size_t)1024 * 1024;           // 1M (2MB)
  bf16_t* Wob = vb  + (size_t)1024 * 1024;           // 4M (8MB) -- ws total 40MB
  // Scratch overlays (all dead or overwritten-later at time of use):
  float* Op0 = (float*)d_ws;          // 16MB over xb+Wqb (dead after gemm_proj)
  float* Op1 = (float*)d_out;         // 16MB; gemm_out overwrites it afterwards
  float* l01 = (float*)Wkb;           // 512KB over Wkb (dead after gemm_proj)
  bf16_t* ab = qb;                    // combine writes after attn's last q read

  dim3 blk(256);
  convert_all<<<7168, blk, 0, stream>>>(x, xb, Wq, Wqb, Wk, Wkb, Wv, Wvb, Wo, Wob);
  gemm_proj<<<768, blk, 0, stream>>>(xb, Wqb, Wkb, Wvb, qb, kb, vb);
  rope_k<<<2048, blk, 0, stream>>>(kb);
  attn_kernel<<<dim3(S_LEN / 128, NHEADS, 2), blk, 0, stream>>>(qb, kb, vb, Op0, Op1, l01);
  combine_kernel<<<2048, blk, 0, stream>>>(Op0, Op1, l01, ab);
  gemm_out<<<512, blk, 0, stream>>>(ab, Wob, (float*)d_out);
}

// Round 5
// 236.557 us; speedup vs baseline: 1.0579x; 1.0579x over previous
//
#include <hip/hip_runtime.h>
#include <hip/hip_bf16.h>
#include <cmath>

typedef __bf16 bf16_t;
typedef __attribute__((ext_vector_type(8))) __bf16 bf16x8;
typedef __attribute__((ext_vector_type(4))) float f32x4;
typedef __attribute__((ext_vector_type(4))) short s16x4;

#define S_LEN 2048
#define DMODEL 2048
#define KVDIM 512
#define NHEADS 32
#define NKV 8
#define HDIM 64

__device__ inline f32x4 zero4() { f32x4 z; z[0]=0.f; z[1]=0.f; z[2]=0.f; z[3]=0.f; return z; }

// Inputs are fp32 (established R2-R6: bf16 misread would NaN; we pass at 1.46e-3).
// One dispatch converts all 5 tensors to bf16. 2048 elems/block:
// x 2048 | Wq 2048 | Wk 512 | Wv 512 | Wo 2048 blocks (7168 total).
__global__ void convert_all(const float* __restrict__ s0, bf16_t* __restrict__ d0,
                            const float* __restrict__ s1, bf16_t* __restrict__ d1,
                            const float* __restrict__ s2, bf16_t* __restrict__ d2,
                            const float* __restrict__ s3, bf16_t* __restrict__ d3,
                            const float* __restrict__ s4, bf16_t* __restrict__ d4) {
  int b = blockIdx.x;
  const float* src; bf16_t* dst; int boff;
  if      (b < 2048) { src = s0; dst = d0; boff = b; }
  else if (b < 4096) { src = s1; dst = d1; boff = b - 2048; }
  else if (b < 4608) { src = s2; dst = d2; boff = b - 4096; }
  else if (b < 5120) { src = s3; dst = d3; boff = b - 4608; }
  else               { src = s4; dst = d4; boff = b - 5120; }
  int idx = (boff * 256 + threadIdx.x) * 8;
  bf16x8 v;
#pragma unroll
  for (int j = 0; j < 8; j++) v[j] = (bf16_t)src[idx + j];
  *(bf16x8*)(dst + idx) = v;
}

// GEMM core: C = A(MxK) * Bt(NxK)^T, bf16 in, fp32 accum. Tile 128 x BN, BK=64,
// 4 waves 2x2 (wave covers 64 x BN/2). BN=64 doubles block count vs BN=128 ->
// 2-3 blocks/CU residency at these matrix sizes (m102: 128^2 @N=2048 is 1/CU-starved).
template <int BN, bool F32OUT>
__device__ __forceinline__ void gemm_core(const bf16_t* __restrict__ A,
                                          const bf16_t* __restrict__ Bt,
                                          void* __restrict__ Cout,
                                          int N, int K, int bm, int bn) {
  constexpr int NT_W = BN / 32;    // 16-col acc tiles per wave
  __shared__ __attribute__((aligned(16))) bf16_t As[128 * 64];
  __shared__ __attribute__((aligned(16))) bf16_t Bs[BN * 64];
  const int tid  = threadIdx.x;
  const int wave = tid >> 6, lane = tid & 63;
  const int wm = wave >> 1, wn = wave & 1;
  const int quad = lane >> 4, lr = lane & 15;
  const int srow = lane >> 3, scol = lane & 7;

  f32x4 acc[4][NT_W];
#pragma unroll
  for (int i = 0; i < 4; i++)
#pragma unroll
    for (int j = 0; j < NT_W; j++) acc[i][j] = zero4();

  for (int k0 = 0; k0 < K; k0 += 64) {
#pragma unroll
    for (int i = 0; i < 4; i++) {
      const bf16_t* gA = A + (size_t)(bm + i * 32 + wave * 8 + srow) * K + k0 + scol * 8;
      bf16_t* lA = As + (i * 32 + wave * 8) * 64;
      __builtin_amdgcn_global_load_lds((const __attribute__((address_space(1))) void*)gA,
                                       (__attribute__((address_space(3))) void*)lA, 16, 0, 0);
    }
#pragma unroll
    for (int i = 0; i < BN / 32; i++) {
      const bf16_t* gB = Bt + (size_t)(bn + i * 32 + wave * 8 + srow) * K + k0 + scol * 8;
      bf16_t* lB = Bs + (i * 32 + wave * 8) * 64;
      __builtin_amdgcn_global_load_lds((const __attribute__((address_space(1))) void*)gB,
                                       (__attribute__((address_space(3))) void*)lB, 16, 0, 0);
    }
    __syncthreads();
#pragma unroll
    for (int ks = 0; ks < 2; ks++) {
      bf16x8 a[4], b[NT_W];
#pragma unroll
      for (int mt = 0; mt < 4; mt++)
        a[mt] = *(const bf16x8*)&As[(wm * 64 + mt * 16 + lr) * 64 + ks * 32 + quad * 8];
#pragma unroll
      for (int nt = 0; nt < NT_W; nt++)
        b[nt] = *(const bf16x8*)&Bs[(wn * (BN / 2) + nt * 16 + lr) * 64 + ks * 32 + quad * 8];
#pragma unroll
      for (int mt = 0; mt < 4; mt++)
#pragma unroll
        for (int nt = 0; nt < NT_W; nt++)
          acc[mt][nt] = __builtin_amdgcn_mfma_f32_16x16x32_bf16(a[mt], b[nt], acc[mt][nt], 0, 0, 0);
    }
    __syncthreads();
  }

#pragma unroll
  for (int mt = 0; mt < 4; mt++)
#pragma unroll
    for (int nt = 0; nt < NT_W; nt++)
#pragma unroll
      for (int r = 0; r < 4; r++) {
        int row = bm + wm * 64 + mt * 16 + quad * 4 + r;
        int col = bn + wn * (BN / 2) + nt * 16 + lr;
        if (F32OUT) ((float*)Cout)[(size_t)row * N + col] = acc[mt][nt][r];
        else ((bf16_t*)Cout)[(size_t)row * N + col] = (bf16_t)acc[mt][nt][r];
      }
}

// All three projections, one dispatch, 768 blocks of 128x64 tiles:
// 0..511: q = x Wq^T; 512..639: k = x Wk^T; 640..767: vT = Wv x^T.
__global__ __launch_bounds__(256) void gemm_proj(const bf16_t* __restrict__ xb,
                                                 const bf16_t* __restrict__ Wqb,
                                                 const bf16_t* __restrict__ Wkb,
                                                 const bf16_t* __restrict__ Wvb,
                                                 bf16_t* __restrict__ qb,
                                                 bf16_t* __restrict__ kb,
                                                 bf16_t* __restrict__ vb) {
  int b = blockIdx.x;
  if (b < 512) {
    gemm_core<64, false>(xb, Wqb, qb, 2048, 2048, (b >> 5) * 128, (b & 31) * 64);
  } else if (b < 640) {
    int r = b - 512;
    gemm_core<64, false>(xb, Wkb, kb, 512, 2048, (r >> 3) * 128, (r & 7) * 64);
  } else {
    int r = b - 640;
    gemm_core<64, false>(Wvb, xb, vb, 2048, 2048, (r >> 5) * 128, (r & 31) * 64);
  }
}

// Final projection: out = attn_out Wo^T, fp32 stores. 512 blocks of 128x64.
__global__ __launch_bounds__(256) void gemm_out(const bf16_t* __restrict__ A,
                                                const bf16_t* __restrict__ Bt,
                                                float* __restrict__ C) {
  int b = blockIdx.x;
  gemm_core<64, true>(A, Bt, C, 2048, 2048, (b >> 5) * 128, (b & 31) * 64);
}

// RoPE on k only (q is roped in-register inside attn).
__global__ void rope_k(bf16_t* __restrict__ kb) {
  int idx = blockIdx.x * 256 + threadIdx.x;
  int s = idx >> 8;                 // 256 pairs per row (KVDIM/2)
  int rem = idx & 255;
  int head = rem >> 5;
  int i = rem & 31;
  float freq = __expf(-0.2878231366f * (float)i);   // 10000^(-i/32)
  float ang = (float)s * freq;
  float sn, cs;
  sincosf(ang, &sn, &cs);
  size_t base = (size_t)s * KVDIM + head * 64 + i;
  float x0 = (float)kb[base];
  float x1 = (float)kb[base + 32];
  kb[base]      = (bf16_t)(x0 * cs - x1 * sn);
  kb[base + 32] = (bf16_t)(x1 * cs + x0 * sn);
}

// Flash attention, S^T formulation, KB=128 key tiles, 32 q-rows/wave (R7).
// R11: T3 2-phase double-buffer. R8-R10 occupancy pushes all failed to beat
// 67us while every pipe sat <=30% busy => latency-bound on the serial per-tile
// chain {stage -> syncthreads(vmcnt0 drain) -> QK -> exp -> PV -> syncthreads}.
// Now: K/V double-buffered (64KB LDS), next tile's global_load_lds issued
// BEFORE computing current tile, ONE barrier per tile (was 2). The barrier's
// vmcnt(0) drain waits on loads issued a full compute phase (~2000cy) ago ->
// ~free. Key-split reverted (residency wasn't the limiter; combine deleted).
// s_setprio(1) wraps MFMA clusters (m191: +4-7% attn).
__global__ __launch_bounds__(256) void attn_kernel(const bf16_t* __restrict__ q,
                                                   const bf16_t* __restrict__ k,
                                                   const bf16_t* __restrict__ vT,
                                                   bf16_t* __restrict__ out) {
  __shared__ __attribute__((aligned(16))) bf16_t Ks[2][128 * 64];   // [key][d]
  __shared__ __attribute__((aligned(16))) bf16_t Vs[2][64 * 128];   // [d][key]
  const int tid  = threadIdx.x;
  const int wave = tid >> 6, lane = tid & 63;
  const int quad = lane >> 4, lr = lane & 15;
  const int srow = lane >> 3, scol = lane & 7;   // K staging: 8 rows x 8 chunks
  const int vrow = lane >> 4, vcol = lane & 15;  // V staging: 4 rows x 16 chunks
  const int cg = scol ^ srow;                    // K swizzle (row&7 == srow)
  const int qt = blockIdx.x, h = blockIdx.y;
  const int hkv = h >> 2;
  const int qrow0 = qt * 128 + wave * 32;        // 32 q-rows per wave
  const int sw = lr & 7;
  const int c0 = (quad ^ sw) * 8;                // K-frag chunk for d<32
  const int c1 = ((quad + 4) ^ sw) * 8;          // d>=32

  // Q B-fragments + in-register RoPE for both 16-row sets
  // (lane holds the exact (d, d+32) pair).
  bf16x8 aqA0, aqA1, aqB0, aqB1;
#pragma unroll
  for (int set = 0; set < 2; set++) {
    int row = qrow0 + set * 16 + lr;
    const bf16_t* qp = q + (size_t)row * DMODEL + h * HDIM + quad * 8;
    bf16x8 r0 = *(const bf16x8*)qp;
    bf16x8 r1 = *(const bf16x8*)(qp + 32);
    float srow_f = (float)row;
    bf16x8 a0, a1;
#pragma unroll
    for (int j = 0; j < 8; j++) {
      float freq = __expf(-0.2878231366f * (float)(quad * 8 + j));
      float sn, cs;
      sincosf(srow_f * freq, &sn, &cs);
      float x0 = (float)r0[j], x1 = (float)r1[j];
      a0[j] = (bf16_t)(x0 * cs - x1 * sn);
      a1[j] = (bf16_t)(x1 * cs + x0 * sn);
    }
    if (set == 0) { aqA0 = a0; aqA1 = a1; } else { aqB0 = a0; aqB1 = a1; }
  }

  f32x4 OA[4], OB[4];         // O^T: (d = mt*16+quad*4+r, qrow = lr)
  float lA = 0.f, lB = 0.f;
#pragma unroll
  for (int mt = 0; mt < 4; mt++) { OA[mt] = zero4(); OB[mt] = zero4(); }

  // Staging macros: 128 key-rows x 64 d (K), 64 d-rows x 128 keys (V^T, swizzled).
#define STAGE_TILE(BUF, KT)                                                              \
  {                                                                                      \
    _Pragma("unroll")                                                                    \
    for (int j = 0; j < 4; j++) {                                                        \
      const bf16_t* gK = k + (size_t)((KT) + wave * 32 + j * 8 + srow) * KVDIM +         \
                         hkv * HDIM + cg * 8;                                            \
      bf16_t* lK = Ks[BUF] + (wave * 32 + j * 8) * 64;                                   \
      __builtin_amdgcn_global_load_lds((const __attribute__((address_space(1))) void*)gK,\
                                       (__attribute__((address_space(3))) void*)lK, 16, 0, 0); \
    }                                                                                    \
    _Pragma("unroll")                                                                    \
    for (int j = 0; j < 4; j++) {                                                        \
      int dg = wave * 16 + j * 4 + vrow;                                                 \
      int cgv = vcol ^ (dg & 7);                                                         \
      const bf16_t* gV = vT + (size_t)(hkv * HDIM + dg) * S_LEN + (KT) + cgv * 8;        \
      bf16_t* lV = Vs[BUF] + (wave * 16 + j * 4) * 128;                                  \
      __builtin_amdgcn_global_load_lds((const __attribute__((address_space(1))) void*)gV,\
                                       (__attribute__((address_space(3))) void*)lV, 16, 0, 0); \
    }                                                                                    \
  }

  // Prologue: stage tile 0 into buffer 0; barrier drains vmcnt.
  STAGE_TILE(0, 0);
  __syncthreads();

  int cur = 0;
  for (int kt = 0; kt < S_LEN; kt += 128) {
    // Prefetch next tile into the other buffer (reads of it finished before
    // the barrier that ended the previous iteration).
    if (kt + 128 < S_LEN) STAGE_TILE(cur ^ 1, kt + 128);
    const bf16_t* Kc = Ks[cur];
    const bf16_t* Vc = Vs[cur];

    // S^T = K Q^T over 8 key-subtiles; K frags shared by both q-sets.
    // exp2 with folded scale: exp(s*0.125) = exp2(s * 0.125*log2e).
    s16x4 bpA[8], bpB[8];
#pragma unroll
    for (int nt = 0; nt < 8; nt++) {
      const int rk = (nt * 16 + lr) * 64;
      bf16x8 kb0 = *(const bf16x8*)&Kc[rk + c0];
      bf16x8 kb1 = *(const bf16x8*)&Kc[rk + c1];
      f32x4 sA = zero4(), sB = zero4();
      __builtin_amdgcn_s_setprio(1);
      sA = __builtin_amdgcn_mfma_f32_16x16x32_bf16(kb0, aqA0, sA, 0, 0, 0);
      sA = __builtin_amdgcn_mfma_f32_16x16x32_bf16(kb1, aqA1, sA, 0, 0, 0);
      sB = __builtin_amdgcn_mfma_f32_16x16x32_bf16(kb0, aqB0, sB, 0, 0, 0);
      sB = __builtin_amdgcn_mfma_f32_16x16x32_bf16(kb1, aqB1, sB, 0, 0, 0);
      __builtin_amdgcn_s_setprio(0);
#pragma unroll
      for (int r = 0; r < 4; r++) {
        float pA = __builtin_amdgcn_exp2f(sA[r] * 0.1803368801f);
        lA += pA;
        bpA[nt][r] = __builtin_bit_cast(short, (bf16_t)pA);
        float pB = __builtin_amdgcn_exp2f(sB[r] * 0.1803368801f);
        lB += pB;
        bpB[nt][r] = __builtin_bit_cast(short, (bf16_t)pB);
      }
    }
    // O^T += V^T P^T: per nt load 4 V A-frags (b64, swizzle-slotted), feed BOTH sets
#pragma unroll
    for (int nt = 0; nt < 8; nt++) {
      const int slot = ((nt * 2 + (quad >> 1)) ^ sw) * 8 + (quad & 1) * 4;
      s16x4 av[4];
#pragma unroll
      for (int mt = 0; mt < 4; mt++)
        av[mt] = *(const s16x4*)&Vc[(mt * 16 + lr) * 128 + slot];
      __builtin_amdgcn_s_setprio(1);
#pragma unroll
      for (int mt = 0; mt < 4; mt++) {
        OA[mt] = __builtin_amdgcn_mfma_f32_16x16x16bf16_1k(av[mt], bpA[nt], OA[mt], 0, 0, 0);
        OB[mt] = __builtin_amdgcn_mfma_f32_16x16x16bf16_1k(av[mt], bpB[nt], OB[mt], 0, 0, 0);
      }
      __builtin_amdgcn_s_setprio(0);
    }
    // Single barrier per tile: drains this tile's prefetch (issued ~full
    // compute phase ago -> near-zero wait) + guards buffer reuse.
    __syncthreads();
    cur ^= 1;
  }
#undef STAGE_TILE

  // l for qrow lr: sum the 4 quad-partials
  lA += __shfl_xor(lA, 16);
  lA += __shfl_xor(lA, 32);
  lB += __shfl_xor(lB, 16);
  lB += __shfl_xor(lB, 32);
  float invA = 1.f / lA;
  float invB = 1.f / lB;

#pragma unroll
  for (int mt = 0; mt < 4; mt++) {
    s16x4 ovA, ovB;
#pragma unroll
    for (int r = 0; r < 4; r++) {
      ovA[r] = __builtin_bit_cast(short, (bf16_t)(OA[mt][r] * invA));
      ovB[r] = __builtin_bit_cast(short, (bf16_t)(OB[mt][r] * invB));
    }
    *(s16x4*)&out[(size_t)(qrow0 + lr) * DMODEL + h * HDIM + mt * 16 + quad * 4] = ovA;
    *(s16x4*)&out[(size_t)(qrow0 + 16 + lr) * DMODEL + h * HDIM + mt * 16 + quad * 4] = ovB;
  }
}

extern "C" void kernel_launch(void* const* d_in, const int* in_sizes, int n_in,
                              void* d_out, int out_size, void* d_ws, size_t ws_size,
                              hipStream_t stream) {
  (void)in_sizes; (void)n_in; (void)out_size; (void)ws_size;
  const float* x  = (const float*)d_in[0];
  const float* Wq = (const float*)d_in[1];
  const float* Wk = (const float*)d_in[2];
  const float* Wv = (const float*)d_in[3];
  const float* Wo = (const float*)d_in[4];

  bf16_t* xb  = (bf16_t*)d_ws;                       // 4M (reused as ab)
  bf16_t* Wqb = xb  + (size_t)4 * 1024 * 1024;       // 4M
  bf16_t* Wkb = Wqb + (size_t)4 * 1024 * 1024;       // 1M
  bf16_t* Wvb = Wkb + (size_t)1024 * 1024;           // 1M
  bf16_t* qb  = Wvb + (size_t)1024 * 1024;           // 4M
  bf16_t* kb  = qb  + (size_t)4 * 1024 * 1024;       // 1M
  bf16_t* vb  = kb  + (size_t)1024 * 1024;           // 1M
  bf16_t* Wob = vb  + (size_t)1024 * 1024;           // 4M (outlives ab=xb)
  bf16_t* ab  = xb;    // x dead after projections

  dim3 blk(256);
  convert_all<<<7168, blk, 0, stream>>>(x, xb, Wq, Wqb, Wk, Wkb, Wv, Wvb, Wo, Wob);
  gemm_proj<<<768, blk, 0, stream>>>(xb, Wqb, Wkb, Wvb, qb, kb, vb);
  rope_k<<<2048, blk, 0, stream>>>(kb);
  attn_kernel<<<dim3(S_LEN / 128, NHEADS), blk, 0, stream>>>(qb, kb, vb, ab);
  gemm_out<<<512, blk, 0, stream>>>(ab, Wob, (float*)d_out);
}